// Round 10
// baseline (1223.036 us; speedup 1.0000x reference)
//
#include <hip/hip_runtime.h>
#include <hip/hip_bf16.h>

// QLSTM: T=512, B=256, D=128, H=256.  z = [x,h] @ W^T + b, W=[4H,384]
// Round 18: r17 (983us; W-in-regs + K-split) + two changes:
//  1) NON-TEMPORAL X LOADS: X is stream-once (67MB); its prefetch stream
//     (256KB/step/XCD) churns the 4MB XCD L2 and evicts hot exchange lines,
//     turning some sc0 polls into ~900cy HBM misses -- each such miss stalls
//     the WHOLE chain-step (period = max over 16 producers). FETCH_SIZE
//     shows ~23MB of unexplained refetch (~700 lines/step). nt loads
//     allocate at LRU -> X stops displacing the exchange working set.
//     (__builtin_nontemporal_load keeps compiler dependency tracking; the
//     prefetch schedule is unchanged.)
//  2) WAVE-PARALLEL GATE ACTIVATIONS: the z-producing thread applies
//     sigmoid/tanh before barrier2 (wave = gate -> uniform branch; bias
//     added there; identical arithmetic order -> bit-identical results).
//     Post-barrier2 tail = 4 LDS reads + fma + 1 tanh + store.
// Everything else r17 verbatim: poll protocol, dual-plane stores, K-split
// x-MFMA post-store, chain = blockIdx&15, LDS footprint pad.

#define T_STEPS 512
#define BATCH   256
#define DIN     128
#define HID     256
#define KDIM    384
#define LDK     520   // comb row stride (shorts): x|h|x' layout
#define GRIDN   256
#define NPOLL   96    // bounded fast-poll tries before sc1 fallback

typedef __attribute__((ext_vector_type(8))) short short8;
typedef __attribute__((ext_vector_type(4))) short short4v;
typedef __attribute__((ext_vector_type(4))) float f32x4;

__device__ __forceinline__ unsigned short f2bf(float f) {
    unsigned u = __float_as_uint(f);
    unsigned r = (u + 0x7FFFu + ((u >> 16) & 1u)) >> 16;
    return (unsigned short)r;
}
__device__ __forceinline__ float bf2f(unsigned short s) {
    return __uint_as_float(((unsigned)s) << 16);
}
__device__ __forceinline__ float sigmoid_f(float x) {
    return 1.f / (1.f + __expf(-x));
}
__device__ __forceinline__ float tanh_f(float x) {
    float e = __expf(2.f * x);
    return 1.f - 2.f / (e + 1.f);
}
// ---- fused poll loads: 4 x dwordx4 + waitcnt in ONE asm block (r4 idiom) ----
__device__ __forceinline__ void poll_load_sc0(const unsigned int* p, uint4& a,
                                              uint4& b, uint4& c, uint4& d) {
    asm volatile(
        "global_load_dwordx4 %0, %4, off sc0\n\t"
        "global_load_dwordx4 %1, %4, off offset:16 sc0\n\t"
        "global_load_dwordx4 %2, %4, off offset:32 sc0\n\t"
        "global_load_dwordx4 %3, %4, off offset:48 sc0\n\t"
        "s_waitcnt vmcnt(0)"
        : "=&v"(a), "=&v"(b), "=&v"(c), "=&v"(d) : "v"(p) : "memory");
}
__device__ __forceinline__ void poll_load_sc1(const unsigned int* p, uint4& a,
                                              uint4& b, uint4& c, uint4& d) {
    asm volatile(
        "global_load_dwordx4 %0, %4, off sc1\n\t"
        "global_load_dwordx4 %1, %4, off offset:16 sc1\n\t"
        "global_load_dwordx4 %2, %4, off offset:32 sc1\n\t"
        "global_load_dwordx4 %3, %4, off offset:48 sc1\n\t"
        "s_waitcnt vmcnt(0)"
        : "=&v"(a), "=&v"(b), "=&v"(c), "=&v"(d) : "v"(p) : "memory");
}
__device__ __forceinline__ void store_sc0_u32(unsigned int* p, unsigned int v) {
    asm volatile("global_store_dword %0, %1, off sc0" :: "v"(p), "v"(v) : "memory");
}
__device__ __forceinline__ void store_sc1_u32(unsigned int* p, unsigned int v) {
    asm volatile("global_store_dword %0, %1, off sc1" :: "v"(p), "v"(v) : "memory");
}
__device__ __forceinline__ unsigned pack2bf(unsigned lo, unsigned hi) {
    return (hi & 0xFFFF0000u) | (lo >> 16);
}
__device__ __forceinline__ bool tags_ok(const uint4& a, const uint4& b,
                                        const uint4& c, const uint4& d,
                                        unsigned tag) {
    return ((a.x ^ tag) & 0xFFFFu) == 0 && ((a.y ^ tag) & 0xFFFFu) == 0 &&
           ((a.z ^ tag) & 0xFFFFu) == 0 && ((a.w ^ tag) & 0xFFFFu) == 0 &&
           ((b.x ^ tag) & 0xFFFFu) == 0 && ((b.y ^ tag) & 0xFFFFu) == 0 &&
           ((b.z ^ tag) & 0xFFFFu) == 0 && ((b.w ^ tag) & 0xFFFFu) == 0 &&
           ((c.x ^ tag) & 0xFFFFu) == 0 && ((c.y ^ tag) & 0xFFFFu) == 0 &&
           ((c.z ^ tag) & 0xFFFFu) == 0 && ((c.w ^ tag) & 0xFFFFu) == 0 &&
           ((d.x ^ tag) & 0xFFFFu) == 0 && ((d.y ^ tag) & 0xFFFFu) == 0 &&
           ((d.z ^ tag) & 0xFFFFu) == 0 && ((d.w ^ tag) & 0xFFFFu) == 0;
}

// ---- pack weights: Wpack[n][k] bf16, n = g*256 + j, row-major [1024][384] ----
__global__ __launch_bounds__(256) void pack_w(
    const float* __restrict__ Wf, const float* __restrict__ Wi,
    const float* __restrict__ Wg, const float* __restrict__ Wo,
    unsigned short* __restrict__ Wp) {
    int idx = blockIdx.x * 256 + threadIdx.x;
    int n = idx / KDIM;
    int k = idx - n * KDIM;
    int g = n >> 8, j = n & 255;
    const float* s = (g == 0) ? Wf : (g == 1) ? Wi : (g == 2) ? Wg : Wo;
    Wp[idx] = f2bf(s[j * KDIM + k]);
}

__global__ __launch_bounds__(256) void pack_b(
    const float* __restrict__ bf, const float* __restrict__ bi,
    const float* __restrict__ bg, const float* __restrict__ bo,
    float* __restrict__ bp) {
    int n = blockIdx.x * 256 + threadIdx.x;
    int g = n >> 8, j = n & 255;
    const float* s = (g == 0) ? bf : (g == 1) ? bi : (g == 2) ? bg : bo;
    bp[n] = s[j];
}

// ---- zero all 4 exchange planes: fast[2] + slow[2] (h_0 = 0, tag 0) ----
__global__ __launch_bounds__(256) void init_k(unsigned int* __restrict__ hxp) {
    int tid = blockIdx.x * 256 + threadIdx.x;   // grid 256 -> 65536
    hxp[tid] = 0u;
    hxp[65536 + tid] = 0u;
    hxp[131072 + tid] = 0u;
    hxp[196608 + tid] = 0u;
}

// ---- persistent LSTM: all 512 steps in one launch ----
__global__ __launch_bounds__(256, 1) void lstm_persist(
    const float* __restrict__ X,            // [T,B,D] fp32
    const unsigned short* __restrict__ W,   // [1024][384] bf16
    const float* __restrict__ bias,         // [1024]
    unsigned int* __restrict__ hxp,         // fast[2][B][H] + slow[2][B][H]
    unsigned short* __restrict__ hist,      // [T][B][H] bf16
    float* __restrict__ out) {
    __shared__ __align__(16) unsigned short comb_s[16 * LDK]; // 16640 B
    __shared__ __align__(16) float z_s[4 * 272];              // 4352 B
    __shared__ __align__(16) char pad_s[46080];  // keep ~67.5KB footprint
    __shared__ int fastok_s;

    const int tid = threadIdx.x;
    // chain = same (blockIdx % 16): same-XCD under round-robin (r11-verified)
    const int bg = blockIdx.x & 15, jg = blockIdx.x >> 4;
    const int b0 = bg * 16, j0 = jg * 16;
    const int wave = tid >> 6, lane = tid & 63;
    const int l16 = lane & 15, quad = lane >> 4;
    const int bi = tid >> 4, jj = tid & 15;
    const int b = b0 + bi, j = j0 + jj;

    // ---- W slice into REGISTERS (r16 proven): wave w = gate, cols j0+l16 ----
    const unsigned short* wrow =
        W + (size_t)(wave * 256 + j0 + l16) * KDIM + quad * 8;
    short8 wb[12];
#pragma unroll
    for (int kt = 0; kt < 12; ++kt) wb[kt] = *(const short8*)(wrow + kt * 32);

    // producer-side bias (gate = wave, col = j0+l16): one scalar covers r=0..3
    const float bsw = bias[wave * 256 + j0 + l16];
    if (tid == 0) {
        fastok_s = 1;
        ((volatile char*)pad_s)[0] = 0;   // keep occupancy pad allocated
    }

    float c_reg = 0.f;
    float h_final = 0.f;

    const unsigned short* arow = &comb_s[l16 * LDK + quad * 8];
    const int hrow = tid >> 4, hc = tid & 15;
    const int xr0 = tid >> 5, xc4 = tid & 31, xr1 = (tid + 256) >> 5;

    // ---- prologue: stage x_0 into x_even; prefetch x_1 (nt); x-MFMA x_0 ----
    {
        const float* x0b = X + b0 * DIN;
        f32x4 t0 = __builtin_nontemporal_load(
            (const f32x4*)(x0b + xr0 * DIN + xc4 * 4));
        f32x4 t1 = __builtin_nontemporal_load(
            (const f32x4*)(x0b + xr1 * DIN + xc4 * 4));
        short4v r;
        r.x = (short)f2bf(t0[0]); r.y = (short)f2bf(t0[1]);
        r.z = (short)f2bf(t0[2]); r.w = (short)f2bf(t0[3]);
        *(short4v*)(&comb_s[xr0 * LDK + xc4 * 4]) = r;
        r.x = (short)f2bf(t1[0]); r.y = (short)f2bf(t1[1]);
        r.z = (short)f2bf(t1[2]); r.w = (short)f2bf(t1[3]);
        *(short4v*)(&comb_s[xr1 * LDK + xc4 * 4]) = r;
    }
    f32x4 xv0 = __builtin_nontemporal_load(
        (const f32x4*)(X + (size_t)BATCH * DIN + b0 * DIN + xr0 * DIN + xc4 * 4));
    f32x4 xv1 = __builtin_nontemporal_load(
        (const f32x4*)(X + (size_t)BATCH * DIN + b0 * DIN + xr1 * DIN + xc4 * 4));
    __syncthreads();

    f32x4 acc_x0 = {0.f, 0.f, 0.f, 0.f}, acc_x1 = {0.f, 0.f, 0.f, 0.f};
#pragma unroll
    for (int kp = 0; kp < 2; ++kp) {   // kt 0..3 on x_even (cols 0..127)
        short8 a0 = *(const short8*)(arow + (2 * kp) * 32);
        short8 a1 = *(const short8*)(arow + (2 * kp + 1) * 32);
        acc_x0 = __builtin_amdgcn_mfma_f32_16x16x32_bf16(a0, wb[2 * kp], acc_x0, 0, 0, 0);
        acc_x1 = __builtin_amdgcn_mfma_f32_16x16x32_bf16(a1, wb[2 * kp + 1], acc_x1, 0, 0, 0);
    }

    for (int k = 0; k < T_STEPS; ++k) {
        const unsigned tag = (unsigned)k;
        const unsigned int* fb =
            hxp + (k & 1) * 65536 + (b0 + hrow) * HID + hc * 16;
        const unsigned int* sb = fb + 131072;    // slow plane
        uint4 a, bq, cq, d;
        const int usefast = fastok_s;            // racy read is fine (hint only)

        // ---- poll h_k: fast (bounded) then slow (guaranteed) ----
        if (usefast) {
            int tries = NPOLL;
            bool ok = false;
            for (;;) {
                poll_load_sc0(fb, a, bq, cq, d);
                if (tags_ok(a, bq, cq, d, tag)) { ok = true; break; }
                if (--tries == 0) break;
            }
            if (!ok) {                       // bounded fallback: ALWAYS succeeds
                fastok_s = 0;
                for (;;) {
                    poll_load_sc1(sb, a, bq, cq, d);
                    if (tags_ok(a, bq, cq, d, tag)) break;
                    __builtin_amdgcn_s_sleep(1);
                }
            }
        } else {
            for (;;) {
                poll_load_sc1(sb, a, bq, cq, d);
                if (tags_ok(a, bq, cq, d, tag)) break;
                __builtin_amdgcn_s_sleep(1);
            }
        }

        // extract 16 bf16 -> comb_s[hrow][128 + hc*16 ..] (h region)
        {
            uint4 p0, p1;
            p0.x = pack2bf(a.x, a.y);   p0.y = pack2bf(a.z, a.w);
            p0.z = pack2bf(bq.x, bq.y); p0.w = pack2bf(bq.z, bq.w);
            p1.x = pack2bf(cq.x, cq.y); p1.y = pack2bf(cq.z, cq.w);
            p1.z = pack2bf(d.x, d.y);   p1.w = pack2bf(d.z, d.w);
            *(uint4*)(&comb_s[hrow * LDK + DIN + hc * 16]) = p0;
            *(uint4*)(&comb_s[hrow * LDK + DIN + hc * 16 + 8]) = p1;
        }
        // stage x_{k+1} into parity region (from regs prefetched last step)
        if (k + 1 < T_STEPS) {
            const int xoff = ((k + 1) & 1) ? 384 : 0;
            short4v r;
            r.x = (short)f2bf(xv0[0]); r.y = (short)f2bf(xv0[1]);
            r.z = (short)f2bf(xv0[2]); r.w = (short)f2bf(xv0[3]);
            *(short4v*)(&comb_s[xr0 * LDK + xoff + xc4 * 4]) = r;
            r.x = (short)f2bf(xv1[0]); r.y = (short)f2bf(xv1[1]);
            r.z = (short)f2bf(xv1[2]); r.w = (short)f2bf(xv1[3]);
            *(short4v*)(&comb_s[xr1 * LDK + xoff + xc4 * 4]) = r;
        }
        __syncthreads();   // barrier 1: h + x_{k+1} staged

        // ---- h-part MFMA (kt 4..11), seeded with precomputed x-part ----
        f32x4 acc0 = acc_x0, acc1 = acc_x1;
#pragma unroll
        for (int kt = 2; kt < 6; ++kt) {   // cols kt*32: 128..383 = h region
            short8 a0 = *(const short8*)(arow + (2 * kt) * 32);
            short8 a1 = *(const short8*)(arow + (2 * kt + 1) * 32);
            acc0 = __builtin_amdgcn_mfma_f32_16x16x32_bf16(a0, wb[2 * kt], acc0, 0, 0, 0);
            acc1 = __builtin_amdgcn_mfma_f32_16x16x32_bf16(a1, wb[2 * kt + 1], acc1, 0, 0, 0);
        }
        // ---- producer-side activation (wave = gate; uniform branch) ----
#pragma unroll
        for (int r = 0; r < 4; ++r) {
            float zz = (acc0[r] + acc1[r]) + bsw;
            float act = (wave == 2) ? tanh_f(zz) : sigmoid_f(zz);
            z_s[wave * 272 + (quad * 4 + r) * 17 + l16] = act;
        }
        __syncthreads();   // barrier 2: activations staged

        // ---- short tail: c/h update; dual-store h FIRST; hist ----
        float fg = z_s[0 * 272 + bi * 17 + jj];
        float ig = z_s[1 * 272 + bi * 17 + jj];
        float gg = z_s[2 * 272 + bi * 17 + jj];
        float og = z_s[3 * 272 + bi * 17 + jj];
        c_reg = fg * c_reg + ig * gg;
        float hval = og * tanh_f(c_reg);
        unsigned short hb = f2bf(hval);
        unsigned int hword = ((unsigned)hb << 16) | (unsigned)(k + 1);
        unsigned int* fdst = hxp + ((k + 1) & 1) * 65536 + b * HID + j;
        store_sc0_u32(fdst, hword);               // fast plane (same-XCD L2)
        store_sc1_u32(fdst + 131072, hword);      // slow plane (proven path)
        hist[(size_t)k * BATCH * HID + b * HID + j] = hb;

        if (k + 1 < T_STEPS) {
            // x prefetch regs for step k+2 (non-temporal)
            if (k + 2 < T_STEPS) {
                const float* xn = X + (size_t)(k + 2) * BATCH * DIN + b0 * DIN;
                xv0 = __builtin_nontemporal_load(
                    (const f32x4*)(xn + xr0 * DIN + xc4 * 4));
                xv1 = __builtin_nontemporal_load(
                    (const f32x4*)(xn + xr1 * DIN + xc4 * 4));
            }
            // ---- post-store x-part MFMA for step k+1 (off the h-chain) ----
            const int xoff = ((k + 1) & 1) ? 384 : 0;
            f32x4 ax0 = {0.f, 0.f, 0.f, 0.f}, ax1 = {0.f, 0.f, 0.f, 0.f};
#pragma unroll
            for (int kp = 0; kp < 2; ++kp) {
                short8 a0 = *(const short8*)(arow + xoff + (2 * kp) * 32);
                short8 a1 = *(const short8*)(arow + xoff + (2 * kp + 1) * 32);
                ax0 = __builtin_amdgcn_mfma_f32_16x16x32_bf16(a0, wb[2 * kp], ax0, 0, 0, 0);
                ax1 = __builtin_amdgcn_mfma_f32_16x16x32_bf16(a1, wb[2 * kp + 1], ax1, 0, 0, 0);
            }
            acc_x0 = ax0; acc_x1 = ax1;
        } else {
            h_final = hval;
        }
    }

    // epilogue: hx (fp32) and cx outputs
    out[T_STEPS * BATCH * 2 + b * HID + j] = h_final;
    out[T_STEPS * BATCH * 2 + BATCH * HID + b * HID + j] = c_reg;
}

// ---- classifier head: one wave per (t,b) row ----
__global__ __launch_bounds__(256) void probs_k(
    const unsigned short* __restrict__ hist, const float* __restrict__ Wc,
    const float* __restrict__ bc, float* __restrict__ out) {
    const int wave = threadIdx.x >> 6, lane = threadIdx.x & 63;
    const size_t row = (size_t)blockIdx.x * 4 + wave;   // row = t*256+b < 131072
    const unsigned short* h = hist + row * HID;
    short4v hv = *(const short4v*)(h + lane * 4);
    const float4 wv = *(const float4*)(Wc + lane * 4);
    float p = bf2f((unsigned short)hv.x) * wv.x + bf2f((unsigned short)hv.y) * wv.y +
              bf2f((unsigned short)hv.z) * wv.z + bf2f((unsigned short)hv.w) * wv.w;
#pragma unroll
    for (int off = 32; off >= 1; off >>= 1) p += __shfl_down(p, off);
    if (lane == 0) {
        float prob = 1.f / (1.f + __expf(-(p + bc[0])));
        out[row * 2]     = prob;
        out[row * 2 + 1] = 1.f - prob;
    }
}

extern "C" void kernel_launch(void* const* d_in, const int* in_sizes, int n_in,
                              void* d_out, int out_size, void* d_ws, size_t ws_size,
                              hipStream_t stream) {
    const float* X  = (const float*)d_in[0];
    const float* Wf = (const float*)d_in[1];
    const float* bfp= (const float*)d_in[2];
    const float* Wi = (const float*)d_in[3];
    const float* bip= (const float*)d_in[4];
    const float* Wg = (const float*)d_in[5];
    const float* bgp= (const float*)d_in[6];
    const float* Wo = (const float*)d_in[7];
    const float* bop= (const float*)d_in[8];
    const float* Wc = (const float*)d_in[9];
    const float* bc = (const float*)d_in[10];
    float* out = (float*)d_out;

    char* ws = (char*)d_ws;
    unsigned short* Wpack = (unsigned short*)(ws);               // 786432 B
    float* bias = (float*)(ws + 786432);                         // 4096 B
    unsigned int* hxp = (unsigned int*)(ws + 790528);            // 1048576 B
    unsigned short* hist = (unsigned short*)(ws + 1839104);      // 67108864 B

    pack_w<<<1536, 256, 0, stream>>>(Wf, Wi, Wg, Wo, Wpack);
    pack_b<<<4, 256, 0, stream>>>(bfp, bip, bgp, bop, bias);
    init_k<<<256, 256, 0, stream>>>(hxp);

    void* kargs[6] = {(void*)&X, (void*)&Wpack, (void*)&bias,
                      (void*)&hxp, (void*)&hist, (void*)&out};
    (void)hipLaunchCooperativeKernel((const void*)lstm_persist, dim3(GRIDN),
                                     dim3(256), kargs, 0, stream);

    probs_k<<<32768, 256, 0, stream>>>(hist, Wc, bc, out);
}

// Round 11
// 1163.191 us; speedup vs baseline: 1.0514x; 1.0514x over previous
//
#include <hip/hip_runtime.h>
#include <hip/hip_bf16.h>
#include <hip/hip_cooperative_groups.h>

namespace cg = cooperative_groups;

// QLSTM: T=512, B=256, D=128, H=256.  z = [x,h] @ W^T + b, W=[4H,384]
// Round 19: r17 core (proven 983us: W-in-regs + K-split) + FULL KERNEL
// FUSION. The bench showed ~119us between end-to-end dur and the lstm
// dispatch: 4 auxiliary launches (pack_w, pack_b, init_k, probs_k) + graph
// gaps. All folded into the one cooperative kernel:
//  - init fold: each block zeros its 1KB hxp slice; grid.sync() before any
//    poll (zeros visible; same-XCD consumers read via shared L2).
//  - pack fold: each block loads its 64 W rows direct from fp32 inputs into
//    wb[12] registers (f2bf inline, wave-uniform source select); biases
//    read direct per thread.
//  - probs fold: after the main loop, grid.sync(), then block (bg,jg)
//    computes probs for rows {t in jg*32..+31} x {b in b0..b0+15}. All 256
//    j of such rows were written by chain bg's 16 blocks -- SAME XCD
//    (r11-verified) -> plain loads after grid sync are coherent via the
//    shared L2, and hist is L2/L3-warm (vs probs_k's cold 64MB re-read).
// Main loop r17 byte-identical (r18's nt-loads + producer-activations
// reverted: both regressed). Poll protocol, dual-plane, K-split, chain
// mapping, LDS footprint: unchanged.

#define T_STEPS 512
#define BATCH   256
#define DIN     128
#define HID     256
#define KDIM    384
#define LDK     520   // comb row stride (shorts): x|h|x' layout
#define GRIDN   256
#define NPOLL   96    // bounded fast-poll tries before sc1 fallback

typedef __attribute__((ext_vector_type(8))) short short8;
typedef __attribute__((ext_vector_type(4))) short short4v;
typedef __attribute__((ext_vector_type(4))) float f32x4;

__device__ __forceinline__ unsigned short f2bf(float f) {
    unsigned u = __float_as_uint(f);
    unsigned r = (u + 0x7FFFu + ((u >> 16) & 1u)) >> 16;
    return (unsigned short)r;
}
__device__ __forceinline__ float bf2f(unsigned short s) {
    return __uint_as_float(((unsigned)s) << 16);
}
__device__ __forceinline__ float sigmoid_f(float x) {
    return 1.f / (1.f + __expf(-x));
}
__device__ __forceinline__ float tanh_f(float x) {
    float e = __expf(2.f * x);
    return 1.f - 2.f / (e + 1.f);
}
// ---- fused poll loads: 4 x dwordx4 + waitcnt in ONE asm block (r4 idiom) ----
__device__ __forceinline__ void poll_load_sc0(const unsigned int* p, uint4& a,
                                              uint4& b, uint4& c, uint4& d) {
    asm volatile(
        "global_load_dwordx4 %0, %4, off sc0\n\t"
        "global_load_dwordx4 %1, %4, off offset:16 sc0\n\t"
        "global_load_dwordx4 %2, %4, off offset:32 sc0\n\t"
        "global_load_dwordx4 %3, %4, off offset:48 sc0\n\t"
        "s_waitcnt vmcnt(0)"
        : "=&v"(a), "=&v"(b), "=&v"(c), "=&v"(d) : "v"(p) : "memory");
}
__device__ __forceinline__ void poll_load_sc1(const unsigned int* p, uint4& a,
                                              uint4& b, uint4& c, uint4& d) {
    asm volatile(
        "global_load_dwordx4 %0, %4, off sc1\n\t"
        "global_load_dwordx4 %1, %4, off offset:16 sc1\n\t"
        "global_load_dwordx4 %2, %4, off offset:32 sc1\n\t"
        "global_load_dwordx4 %3, %4, off offset:48 sc1\n\t"
        "s_waitcnt vmcnt(0)"
        : "=&v"(a), "=&v"(b), "=&v"(c), "=&v"(d) : "v"(p) : "memory");
}
__device__ __forceinline__ void store_sc0_u32(unsigned int* p, unsigned int v) {
    asm volatile("global_store_dword %0, %1, off sc0" :: "v"(p), "v"(v) : "memory");
}
__device__ __forceinline__ void store_sc1_u32(unsigned int* p, unsigned int v) {
    asm volatile("global_store_dword %0, %1, off sc1" :: "v"(p), "v"(v) : "memory");
}
__device__ __forceinline__ unsigned pack2bf(unsigned lo, unsigned hi) {
    return (hi & 0xFFFF0000u) | (lo >> 16);
}
__device__ __forceinline__ bool tags_ok(const uint4& a, const uint4& b,
                                        const uint4& c, const uint4& d,
                                        unsigned tag) {
    return ((a.x ^ tag) & 0xFFFFu) == 0 && ((a.y ^ tag) & 0xFFFFu) == 0 &&
           ((a.z ^ tag) & 0xFFFFu) == 0 && ((a.w ^ tag) & 0xFFFFu) == 0 &&
           ((b.x ^ tag) & 0xFFFFu) == 0 && ((b.y ^ tag) & 0xFFFFu) == 0 &&
           ((b.z ^ tag) & 0xFFFFu) == 0 && ((b.w ^ tag) & 0xFFFFu) == 0 &&
           ((c.x ^ tag) & 0xFFFFu) == 0 && ((c.y ^ tag) & 0xFFFFu) == 0 &&
           ((c.z ^ tag) & 0xFFFFu) == 0 && ((c.w ^ tag) & 0xFFFFu) == 0 &&
           ((d.x ^ tag) & 0xFFFFu) == 0 && ((d.y ^ tag) & 0xFFFFu) == 0 &&
           ((d.z ^ tag) & 0xFFFFu) == 0 && ((d.w ^ tag) & 0xFFFFu) == 0;
}

// ---- single fused persistent kernel: init + pack + 512 LSTM steps + probs --
__global__ __launch_bounds__(256, 1) void lstm_persist(
    const float* __restrict__ X,            // [T,B,D] fp32
    const float* __restrict__ Wf, const float* __restrict__ bfp,
    const float* __restrict__ Wi, const float* __restrict__ bip,
    const float* __restrict__ Wg, const float* __restrict__ bgp,
    const float* __restrict__ Wo, const float* __restrict__ bop,
    const float* __restrict__ Wc, const float* __restrict__ bc,
    unsigned int* __restrict__ hxp,         // fast[2][B][H] + slow[2][B][H]
    unsigned short* __restrict__ hist,      // [T][B][H] bf16
    float* __restrict__ out) {
    __shared__ __align__(16) unsigned short comb_s[16 * LDK]; // 16640 B
    __shared__ __align__(16) float z_s[4 * 272];              // 4352 B
    __shared__ __align__(16) char pad_s[46080];  // keep ~67.5KB footprint
    __shared__ int fastok_s;

    const int tid = threadIdx.x;
    // chain = same (blockIdx % 16): same-XCD under round-robin (r11-verified)
    const int bg = blockIdx.x & 15, jg = blockIdx.x >> 4;
    const int b0 = bg * 16, j0 = jg * 16;
    const int wave = tid >> 6, lane = tid & 63;
    const int l16 = lane & 15, quad = lane >> 4;
    const int bi = tid >> 4, jj = tid & 15;
    const int b = b0 + bi, j = j0 + jj;

    // ---- init fold: zero own hxp slice (all 4 planes) ----
    {
        int idx = blockIdx.x * 256 + tid;
        hxp[idx] = 0u;
        hxp[65536 + idx] = 0u;
        hxp[131072 + idx] = 0u;
        hxp[196608 + idx] = 0u;
    }

    // ---- pack fold: W slice fp32 -> bf16 registers (wave = gate) ----
    const float* wsrc = (wave == 0) ? Wf : (wave == 1) ? Wi
                      : (wave == 2) ? Wg : Wo;
    const float* wr = wsrc + (size_t)(j0 + l16) * KDIM + quad * 8;
    short8 wb[12];
#pragma unroll
    for (int kt = 0; kt < 12; ++kt) {
        f32x4 lo = *(const f32x4*)(wr + kt * 32);
        f32x4 hi = *(const f32x4*)(wr + kt * 32 + 4);
        short8 v;
        v[0] = (short)f2bf(lo[0]); v[1] = (short)f2bf(lo[1]);
        v[2] = (short)f2bf(lo[2]); v[3] = (short)f2bf(lo[3]);
        v[4] = (short)f2bf(hi[0]); v[5] = (short)f2bf(hi[1]);
        v[6] = (short)f2bf(hi[2]); v[7] = (short)f2bf(hi[3]);
        wb[kt] = v;
    }
    const float bs0 = bfp[j];
    const float bs1 = bip[j];
    const float bs2 = bgp[j];
    const float bs3 = bop[j];
    if (tid == 0) {
        fastok_s = 1;
        ((volatile char*)pad_s)[0] = 0;   // keep occupancy pad allocated
    }

    cg::this_grid().sync();   // hxp zeros visible before any poll

    float c_reg = 0.f;
    float h_final = 0.f;

    const unsigned short* arow = &comb_s[l16 * LDK + quad * 8];
    const int hrow = tid >> 4, hc = tid & 15;
    const int xr0 = tid >> 5, xc4 = tid & 31, xr1 = (tid + 256) >> 5;

    // ---- prologue: stage x_0 into x_even; prefetch x_1; x-MFMA for x_0 ----
    {
        const float* x0b = X + b0 * DIN;
        float4 t0 = *(const float4*)(x0b + xr0 * DIN + xc4 * 4);
        float4 t1 = *(const float4*)(x0b + xr1 * DIN + xc4 * 4);
        short4v r;
        r.x = (short)f2bf(t0.x); r.y = (short)f2bf(t0.y);
        r.z = (short)f2bf(t0.z); r.w = (short)f2bf(t0.w);
        *(short4v*)(&comb_s[xr0 * LDK + xc4 * 4]) = r;
        r.x = (short)f2bf(t1.x); r.y = (short)f2bf(t1.y);
        r.z = (short)f2bf(t1.z); r.w = (short)f2bf(t1.w);
        *(short4v*)(&comb_s[xr1 * LDK + xc4 * 4]) = r;
    }
    float4 xv0 = *(const float4*)(X + (size_t)BATCH * DIN + b0 * DIN + xr0 * DIN + xc4 * 4);
    float4 xv1 = *(const float4*)(X + (size_t)BATCH * DIN + b0 * DIN + xr1 * DIN + xc4 * 4);
    __syncthreads();

    f32x4 acc_x0 = {0.f, 0.f, 0.f, 0.f}, acc_x1 = {0.f, 0.f, 0.f, 0.f};
#pragma unroll
    for (int kp = 0; kp < 2; ++kp) {   // kt 0..3 on x_even (cols 0..127)
        short8 a0 = *(const short8*)(arow + (2 * kp) * 32);
        short8 a1 = *(const short8*)(arow + (2 * kp + 1) * 32);
        acc_x0 = __builtin_amdgcn_mfma_f32_16x16x32_bf16(a0, wb[2 * kp], acc_x0, 0, 0, 0);
        acc_x1 = __builtin_amdgcn_mfma_f32_16x16x32_bf16(a1, wb[2 * kp + 1], acc_x1, 0, 0, 0);
    }

    for (int k = 0; k < T_STEPS; ++k) {
        const unsigned tag = (unsigned)k;
        const unsigned int* fb =
            hxp + (k & 1) * 65536 + (b0 + hrow) * HID + hc * 16;
        const unsigned int* sb = fb + 131072;    // slow plane
        uint4 a, bq, cq, d;
        const int usefast = fastok_s;            // racy read is fine (hint only)

        // ---- poll h_k: fast (bounded) then slow (guaranteed) ----
        if (usefast) {
            int tries = NPOLL;
            bool ok = false;
            for (;;) {
                poll_load_sc0(fb, a, bq, cq, d);
                if (tags_ok(a, bq, cq, d, tag)) { ok = true; break; }
                if (--tries == 0) break;
            }
            if (!ok) {                       // bounded fallback: ALWAYS succeeds
                fastok_s = 0;
                for (;;) {
                    poll_load_sc1(sb, a, bq, cq, d);
                    if (tags_ok(a, bq, cq, d, tag)) break;
                    __builtin_amdgcn_s_sleep(1);
                }
            }
        } else {
            for (;;) {
                poll_load_sc1(sb, a, bq, cq, d);
                if (tags_ok(a, bq, cq, d, tag)) break;
                __builtin_amdgcn_s_sleep(1);
            }
        }

        // extract 16 bf16 -> comb_s[hrow][128 + hc*16 ..] (h region)
        {
            uint4 p0, p1;
            p0.x = pack2bf(a.x, a.y);   p0.y = pack2bf(a.z, a.w);
            p0.z = pack2bf(bq.x, bq.y); p0.w = pack2bf(bq.z, bq.w);
            p1.x = pack2bf(cq.x, cq.y); p1.y = pack2bf(cq.z, cq.w);
            p1.z = pack2bf(d.x, d.y);   p1.w = pack2bf(d.z, d.w);
            *(uint4*)(&comb_s[hrow * LDK + DIN + hc * 16]) = p0;
            *(uint4*)(&comb_s[hrow * LDK + DIN + hc * 16 + 8]) = p1;
        }
        // stage x_{k+1} into parity region (from regs prefetched last step)
        if (k + 1 < T_STEPS) {
            const int xoff = ((k + 1) & 1) ? 384 : 0;
            short4v r;
            r.x = (short)f2bf(xv0.x); r.y = (short)f2bf(xv0.y);
            r.z = (short)f2bf(xv0.z); r.w = (short)f2bf(xv0.w);
            *(short4v*)(&comb_s[xr0 * LDK + xoff + xc4 * 4]) = r;
            r.x = (short)f2bf(xv1.x); r.y = (short)f2bf(xv1.y);
            r.z = (short)f2bf(xv1.z); r.w = (short)f2bf(xv1.w);
            *(short4v*)(&comb_s[xr1 * LDK + xoff + xc4 * 4]) = r;
        }
        __syncthreads();   // barrier 1: h + x_{k+1} staged

        // ---- h-part MFMA (kt 4..11), seeded with precomputed x-part ----
        f32x4 acc0 = acc_x0, acc1 = acc_x1;
#pragma unroll
        for (int kt = 2; kt < 6; ++kt) {   // cols kt*32: 128..383 = h region
            short8 a0 = *(const short8*)(arow + (2 * kt) * 32);
            short8 a1 = *(const short8*)(arow + (2 * kt + 1) * 32);
            acc0 = __builtin_amdgcn_mfma_f32_16x16x32_bf16(a0, wb[2 * kt], acc0, 0, 0, 0);
            acc1 = __builtin_amdgcn_mfma_f32_16x16x32_bf16(a1, wb[2 * kt + 1], acc1, 0, 0, 0);
        }
#pragma unroll
        for (int r = 0; r < 4; ++r)
            z_s[wave * 272 + (quad * 4 + r) * 17 + l16] = acc0[r] + acc1[r];
        __syncthreads();   // barrier 2: z staged

        // ---- gates; h dual-store FIRST (critical); hist ----
        float zf = z_s[0 * 272 + bi * 17 + jj] + bs0;
        float zi = z_s[1 * 272 + bi * 17 + jj] + bs1;
        float zg = z_s[2 * 272 + bi * 17 + jj] + bs2;
        float zo = z_s[3 * 272 + bi * 17 + jj] + bs3;
        float fg = sigmoid_f(zf);
        float ig = sigmoid_f(zi);
        float gg = tanh_f(zg);
        float og = sigmoid_f(zo);
        c_reg = fg * c_reg + ig * gg;
        float hval = og * tanh_f(c_reg);
        unsigned short hb = f2bf(hval);
        unsigned int hword = ((unsigned)hb << 16) | (unsigned)(k + 1);
        unsigned int* fdst = hxp + ((k + 1) & 1) * 65536 + b * HID + j;
        store_sc0_u32(fdst, hword);               // fast plane (same-XCD L2)
        store_sc1_u32(fdst + 131072, hword);      // slow plane (proven path)
        hist[(size_t)k * BATCH * HID + b * HID + j] = hb;

        if (k + 1 < T_STEPS) {
            // x prefetch regs for step k+2
            if (k + 2 < T_STEPS) {
                const float* xn = X + (size_t)(k + 2) * BATCH * DIN + b0 * DIN;
                xv0 = *(const float4*)(xn + xr0 * DIN + xc4 * 4);
                xv1 = *(const float4*)(xn + xr1 * DIN + xc4 * 4);
            }
            // ---- post-store x-part MFMA for step k+1 (off the h-chain) ----
            const int xoff = ((k + 1) & 1) ? 384 : 0;
            f32x4 ax0 = {0.f, 0.f, 0.f, 0.f}, ax1 = {0.f, 0.f, 0.f, 0.f};
#pragma unroll
            for (int kp = 0; kp < 2; ++kp) {
                short8 a0 = *(const short8*)(arow + xoff + (2 * kp) * 32);
                short8 a1 = *(const short8*)(arow + xoff + (2 * kp + 1) * 32);
                ax0 = __builtin_amdgcn_mfma_f32_16x16x32_bf16(a0, wb[2 * kp], ax0, 0, 0, 0);
                ax1 = __builtin_amdgcn_mfma_f32_16x16x32_bf16(a1, wb[2 * kp + 1], ax1, 0, 0, 0);
            }
            acc_x0 = ax0; acc_x1 = ax1;
        } else {
            h_final = hval;
        }
    }

    // epilogue: hx (fp32) and cx outputs
    out[T_STEPS * BATCH * 2 + b * HID + j] = h_final;
    out[T_STEPS * BATCH * 2 + BATCH * HID + b * HID + j] = c_reg;

    // ---- probs fold: all hist writes complete; same-XCD rows are L2-hot ----
    cg::this_grid().sync();
    {
        const float bias_c = bc[0];
        const float4 wv = *(const float4*)(Wc + lane * 4);
        for (int i = 0; i < 128; ++i) {
            const int lr = wave * 128 + i;          // 0..511
            const int t = jg * 32 + (lr & 31);      // chain bg wrote these rows
            const int bb = b0 + (lr >> 5);
            const unsigned short* h =
                hist + (size_t)t * BATCH * HID + (size_t)bb * HID;
            short4v hv = *(const short4v*)(h + lane * 4);
            float p = bf2f((unsigned short)hv.x) * wv.x +
                      bf2f((unsigned short)hv.y) * wv.y +
                      bf2f((unsigned short)hv.z) * wv.z +
                      bf2f((unsigned short)hv.w) * wv.w;
#pragma unroll
            for (int off = 32; off >= 1; off >>= 1) p += __shfl_down(p, off);
            if (lane == 0) {
                float prob = 1.f / (1.f + __expf(-(p + bias_c)));
                const size_t row = (size_t)t * BATCH + bb;
                out[row * 2]     = prob;
                out[row * 2 + 1] = 1.f - prob;
            }
        }
    }
}

extern "C" void kernel_launch(void* const* d_in, const int* in_sizes, int n_in,
                              void* d_out, int out_size, void* d_ws, size_t ws_size,
                              hipStream_t stream) {
    const float* X  = (const float*)d_in[0];
    const float* Wf = (const float*)d_in[1];
    const float* bfp= (const float*)d_in[2];
    const float* Wi = (const float*)d_in[3];
    const float* bip= (const float*)d_in[4];
    const float* Wg = (const float*)d_in[5];
    const float* bgp= (const float*)d_in[6];
    const float* Wo = (const float*)d_in[7];
    const float* bop= (const float*)d_in[8];
    const float* Wc = (const float*)d_in[9];
    const float* bc = (const float*)d_in[10];
    float* out = (float*)d_out;

    char* ws = (char*)d_ws;
    unsigned int* hxp = (unsigned int*)(ws + 790528);            // 1048576 B
    unsigned short* hist = (unsigned short*)(ws + 1839104);      // 67108864 B

    void* kargs[14] = {(void*)&X,
                       (void*)&Wf, (void*)&bfp,
                       (void*)&Wi, (void*)&bip,
                       (void*)&Wg, (void*)&bgp,
                       (void*)&Wo, (void*)&bop,
                       (void*)&Wc, (void*)&bc,
                       (void*)&hxp, (void*)&hist, (void*)&out};
    (void)hipLaunchCooperativeKernel((const void*)lstm_persist, dim3(GRIDN),
                                     dim3(256), kargs, 0, stream);
}